// Round 13
// baseline (189.153 us; speedup 1.0000x reference)
//
#include <hip/hip_runtime.h>

// EnhancedMoEModel: B=524288, D=32, H=64, H2=32, E=8, O=1. fp32 in/out.
// out[b] = sum_e sigmoid(relu(relu(x W1e + b1e) W2e + b2e) W3e + b3e) * probs[b,e]
//
// R21: expert-stationary waves with FORCED register residency. R20 failed
// because hipcc sank the loop-invariant weight loads back into the loop
// (VGPR=56 < the 61-reg weight set; no spill; 97us with per-iter global
// reloads + barrier convoy). Fixes:
//  (1) asm volatile("" : "+v") pins on all weight/bias registers after the
//      prologue loads -- volatile asm output cannot be rematerialized.
//  (2) one barrier per 512 rows (was 8): partials in LDS [8][512] f32,
//      each wave writes only its expert slice; parallel per-wave reduce.
//  (3) RT=2 row-tiles with 1-deep x/probs prefetch in raw f32x4 regs
//      (pack at use) -- x load latency hidden without barrier convoy.
// In-loop per 32 rows: 18 MFMA, 4 LDS broadcast reads, 2 LDS writes,
// 6 VMEM. Floor max(MFMA 18.6us, VALU ~7us, HBM ~13us).
//
// Fragment math (verified through R20's passing run, dtype-independent
// C/D layout): 16x16x32 MFMA, A[m=lane&15][k=8q+j], B[k=8q+j][n=lane&15],
// D[m=4q+r][n]. hmap(mt,n)=32(mt>>1)+8(n>>2)+4(mt&1)+(n&3) makes layer-N
// outputs exactly the next layer's B-fragment. L3 A = w3 replicated over
// rows -> every lane's s.x = value for its row n.
//
// img layout (bytes): [0,65536) weight frags F*16 (w1: F=e*256+64mt+16q+n;
// w2: F=2048+e*256+128kb2+64mt2+16q+n); [65536,67584) b1 frags f32x4
// idx=e*16+mt*4+q; [67584,68608) b2 frags idx=e*8+mt2*4+q; [68608,69120)
// a3 frags f16x8 idx=e*4+q; [69120,69152) b3 f32[8].

typedef __attribute__((ext_vector_type(8))) _Float16 f16x8;
typedef __attribute__((ext_vector_type(2))) __fp16 h16x2;
typedef __attribute__((ext_vector_type(4))) float f32x4;
typedef union { f16x8 v; unsigned u[4]; } Fu;

__device__ __forceinline__ unsigned pkh(float lo, float hi) {
    union { h16x2 v; unsigned u; } t;
    t.v = __builtin_amdgcn_cvt_pkrtz(lo, hi);
    return t.u;
}

__device__ __forceinline__ unsigned relu2(unsigned a) {
    unsigned r;
    asm("v_pk_max_f16 %0, %1, 0" : "=v"(r) : "v"(a));
    return r;
}

__device__ __forceinline__ float sigf(float s) {
    return 1.f / (1.f + __expf(-s));
}

#define MFMA32(a, b, c) __builtin_amdgcn_mfma_f32_16x16x32_f16((a), (b), (c), 0, 0, 0)
#define PINV(v) asm volatile("" : "+v"(v))

__global__ __launch_bounds__(1024)
void build_image(const float* __restrict__ W1, const float* __restrict__ b1,
                 const float* __restrict__ W2, const float* __restrict__ b2,
                 const float* __restrict__ W3, const float* __restrict__ b3,
                 char* __restrict__ ws) {
    const int tid = threadIdx.x;
    #pragma unroll
    for (int k = 0; k < 4; ++k) {
        const int F = tid + k * 1024;
        const int e = (F >> 8) & 7, s = F & 255;
        const int qq = (s >> 4) & 3, nn = s & 15;
        const float* src;
        int stride;
        if (F < 2048) {          // W1[e][d=8qq+j][hmap(mt,nn)], j strides d
            const int mt = s >> 6;
            const int h = 32 * (mt >> 1) + 8 * (nn >> 2) + 4 * (mt & 1) + (nn & 3);
            src = W1 + (e * 32 + 8 * qq) * 64 + h;
            stride = 64;
        } else {                 // W2[e][h=32kb2+8qq+j][h2map(mt2,nn)], j strides h
            const int kb2 = (s >> 7) & 1, mt2 = (s >> 6) & 1;
            const int h2 = 8 * (nn >> 2) + 4 * mt2 + (nn & 3);
            src = W2 + (e * 64 + 32 * kb2 + 8 * qq) * 32 + h2;
            stride = 32;
        }
        union { f16x8 v; unsigned u[4]; } t;
        t.u[0] = pkh(src[0 * stride], src[1 * stride]);
        t.u[1] = pkh(src[2 * stride], src[3 * stride]);
        t.u[2] = pkh(src[4 * stride], src[5 * stride]);
        t.u[3] = pkh(src[6 * stride], src[7 * stride]);
        *(f16x8*)(ws + F * 16) = t.v;
    }
    if (tid < 128) {                       // b1 frags
        const int e = tid >> 4, mt = (tid >> 2) & 3, q = tid & 3;
        *(f32x4*)(ws + 65536 + tid * 16) =
            *(const f32x4*)(b1 + e * 64 + 32 * (mt >> 1) + 4 * (mt & 1) + 8 * q);
    } else if (tid < 192) {                // b2 frags
        const int i = tid - 128, e = i >> 3, mt2 = (i >> 2) & 1, q = i & 3;
        *(f32x4*)(ws + 67584 + i * 16) =
            *(const f32x4*)(b2 + e * 32 + 4 * mt2 + 8 * q);
    } else if (tid < 224) {                // a3 frags (pre-packed f16)
        const int i = tid - 192, e = i >> 2, q = i & 3;
        const f32x4 lo = *(const f32x4*)(W3 + e * 32 + 8 * q);
        const f32x4 hi = *(const f32x4*)(W3 + e * 32 + 8 * q + 4);
        union { f16x8 v; unsigned u[4]; } a;
        a.u[0] = pkh(lo.x, lo.y); a.u[1] = pkh(lo.z, lo.w);
        a.u[2] = pkh(hi.x, hi.y); a.u[3] = pkh(hi.z, hi.w);
        *(f16x8*)(ws + 68608 + i * 16) = a.v;
    } else if (tid < 232) {                // b3
        const int i = tid - 224;
        *(float*)(ws + 69120 + i * 4) = b3[i];
    }
}

__global__ __launch_bounds__(512, 4)
void moe_fused(const float* __restrict__ x, const float* __restrict__ probs,
               const char* __restrict__ img, float* __restrict__ out) {
    // LDS: [0,16384) partials [8][512] f32; [16384,18432) b1 frag copy.
    __shared__ __attribute__((aligned(16))) char lds[18432];
    const int tid = threadIdx.x;
    const int w = tid >> 6, lane = tid & 63, n = lane & 15, q = lane >> 4;
    const int e = w;                        // this wave's expert, forever

    if (tid < 128)                          // b1 frags -> LDS
        *(f32x4*)(lds + 16384 + tid * 16) = *(const f32x4*)(img + 65536 + tid * 16);

    // ---- weight prologue: this expert's frags -> registers, ONCE, pinned.
    const int lo = n * 16 + q * 256;        // lane offset inside a 1KB tile
    Fu w1r0, w1r1, w1r2, w1r3, w2r00, w2r01, w2r10, w2r11, a3r;
    w1r0.v = *(const f16x8*)(img + e * 4096 + 0 * 1024 + lo);
    w1r1.v = *(const f16x8*)(img + e * 4096 + 1 * 1024 + lo);
    w1r2.v = *(const f16x8*)(img + e * 4096 + 2 * 1024 + lo);
    w1r3.v = *(const f16x8*)(img + e * 4096 + 3 * 1024 + lo);
    // w2 frag (mt2,kb2) at img 32768 + e*4096 + kb2*2048 + mt2*1024 + lo
    w2r00.v = *(const f16x8*)(img + 32768 + e * 4096 + 0 * 2048 + 0 * 1024 + lo);
    w2r01.v = *(const f16x8*)(img + 32768 + e * 4096 + 1 * 2048 + 0 * 1024 + lo);
    w2r10.v = *(const f16x8*)(img + 32768 + e * 4096 + 0 * 2048 + 1 * 1024 + lo);
    w2r11.v = *(const f16x8*)(img + 32768 + e * 4096 + 1 * 2048 + 1 * 1024 + lo);
    a3r.v = *(const f16x8*)(img + 68608 + e * 64 + q * 16);
    f32x4 b2r0 = *(const f32x4*)(img + 67584 + e * 128 + 0 * 64 + q * 16);
    f32x4 b2r1 = *(const f32x4*)(img + 67584 + e * 128 + 1 * 64 + q * 16);
    const float b3v = *(const float*)(img + 69120 + e * 4);
    PINV(w1r0.v); PINV(w1r1.v); PINV(w1r2.v); PINV(w1r3.v);
    PINV(w2r00.v); PINV(w2r01.v); PINV(w2r10.v); PINV(w2r11.v);
    PINV(a3r.v); PINV(b2r0); PINV(b2r1);

    const char* bb1 = lds + 16384 + e * 256 + q * 16;   // + mt*64
    const int base = blockIdx.x * 512;
    const float* xp0 = x + (size_t)(base + n) * 32 + q * 8;  // +it*1024, +rt*512
    const float* pb = probs + (size_t)(base + n) * 8 + e;    // +(it*32+rt*16)*8
    float* pl = (float*)lds + e * 512;                       // partial row slice

    __syncthreads();                        // b1 copy visible

    // ---- prefetch iter 0 (raw f32x4; pack at use)
    f32x4 xa0n = *(const f32x4*)(xp0);
    f32x4 xb0n = *(const f32x4*)(xp0 + 4);
    f32x4 xa1n = *(const f32x4*)(xp0 + 512);
    f32x4 xb1n = *(const f32x4*)(xp0 + 516);
    float p0n = pb[0], p1n = pb[128];

    #pragma unroll 1
    for (int it = 0; it < 16; ++it) {
        // pack current x fragments
        Fu xf0, xf1;
        xf0.u[0] = pkh(xa0n.x, xa0n.y); xf0.u[1] = pkh(xa0n.z, xa0n.w);
        xf0.u[2] = pkh(xb0n.x, xb0n.y); xf0.u[3] = pkh(xb0n.z, xb0n.w);
        xf1.u[0] = pkh(xa1n.x, xa1n.y); xf1.u[1] = pkh(xa1n.z, xa1n.w);
        xf1.u[2] = pkh(xb1n.x, xb1n.y); xf1.u[3] = pkh(xb1n.z, xb1n.w);
        const float p0 = p0n, p1 = p1n;

        // prefetch iter it+1 (uniform branch; loads drain under compute)
        if (it < 15) {
            const float* xq = xp0 + (it + 1) * 1024;
            xa0n = *(const f32x4*)(xq);
            xb0n = *(const f32x4*)(xq + 4);
            xa1n = *(const f32x4*)(xq + 512);
            xb1n = *(const f32x4*)(xq + 516);
            p0n = pb[(it + 1) * 256];
            p1n = pb[(it + 1) * 256 + 128];
        }

        // Layer 1: 4 mt x 2 rt; bias from LDS broadcast.
        Fu P00, P01, P10, P11;              // P<rt><kb2>
        {
            const f32x4 bf0 = *(const f32x4*)(bb1 + 0 * 64);
            const f32x4 bf1 = *(const f32x4*)(bb1 + 1 * 64);
            const f32x4 bf2 = *(const f32x4*)(bb1 + 2 * 64);
            const f32x4 bf3 = *(const f32x4*)(bb1 + 3 * 64);
            f32x4 c;
            c = MFMA32(w1r0.v, xf0.v, bf0);
            P00.u[0] = relu2(pkh(c.x, c.y)); P00.u[1] = relu2(pkh(c.z, c.w));
            c = MFMA32(w1r0.v, xf1.v, bf0);
            P10.u[0] = relu2(pkh(c.x, c.y)); P10.u[1] = relu2(pkh(c.z, c.w));
            c = MFMA32(w1r1.v, xf0.v, bf1);
            P00.u[2] = relu2(pkh(c.x, c.y)); P00.u[3] = relu2(pkh(c.z, c.w));
            c = MFMA32(w1r1.v, xf1.v, bf1);
            P10.u[2] = relu2(pkh(c.x, c.y)); P10.u[3] = relu2(pkh(c.z, c.w));
            c = MFMA32(w1r2.v, xf0.v, bf2);
            P01.u[0] = relu2(pkh(c.x, c.y)); P01.u[1] = relu2(pkh(c.z, c.w));
            c = MFMA32(w1r2.v, xf1.v, bf2);
            P11.u[0] = relu2(pkh(c.x, c.y)); P11.u[1] = relu2(pkh(c.z, c.w));
            c = MFMA32(w1r3.v, xf0.v, bf3);
            P01.u[2] = relu2(pkh(c.x, c.y)); P01.u[3] = relu2(pkh(c.z, c.w));
            c = MFMA32(w1r3.v, xf1.v, bf3);
            P11.u[2] = relu2(pkh(c.x, c.y)); P11.u[3] = relu2(pkh(c.z, c.w));
        }

        // Layer 2: 2 mt2 x 2 kb2 x 2 rt; bias from pinned regs.
        Fu PC0, PC1;
        {
            f32x4 c0 = b2r0, c1 = b2r0;
            c0 = MFMA32(w2r00.v, P00.v, c0); c0 = MFMA32(w2r01.v, P01.v, c0);
            c1 = MFMA32(w2r00.v, P10.v, c1); c1 = MFMA32(w2r01.v, P11.v, c1);
            PC0.u[0] = relu2(pkh(c0.x, c0.y)); PC0.u[1] = relu2(pkh(c0.z, c0.w));
            PC1.u[0] = relu2(pkh(c1.x, c1.y)); PC1.u[1] = relu2(pkh(c1.z, c1.w));
            f32x4 d0 = b2r1, d1 = b2r1;
            d0 = MFMA32(w2r10.v, P00.v, d0); d0 = MFMA32(w2r11.v, P01.v, d0);
            d1 = MFMA32(w2r10.v, P10.v, d1); d1 = MFMA32(w2r11.v, P11.v, d1);
            PC0.u[2] = relu2(pkh(d0.x, d0.y)); PC0.u[3] = relu2(pkh(d0.z, d0.w));
            PC1.u[2] = relu2(pkh(d1.x, d1.y)); PC1.u[3] = relu2(pkh(d1.z, d1.w));
        }

        // Layer 3 + sigmoid + prob weight -> own expert's partial slice.
        const f32x4 cb = {b3v, b3v, b3v, b3v};
        const f32x4 s0 = MFMA32(a3r.v, PC0.v, cb);
        const f32x4 s1 = MFMA32(a3r.v, PC1.v, cb);
        const float g0 = sigf(s0.x) * p0;
        const float g1 = sigf(s1.x) * p1;
        if (q == 0) {
            pl[it * 32 + n] = g0;
            pl[it * 32 + 16 + n] = g1;
        }
    }

    __syncthreads();                        // all partials visible

    // ---- parallel epilogue: wave w reduces rows [w*64, w*64+64).
    {
        const float* pr = (const float*)lds + w * 64 + lane;
        float s = 0.f;
        #pragma unroll
        for (int ee = 0; ee < 8; ++ee) s += pr[ee * 512];
        out[base + w * 64 + lane] = s;
    }
}

extern "C" void kernel_launch(void* const* d_in, const int* in_sizes, int n_in,
                              void* d_out, int out_size, void* d_ws, size_t ws_size,
                              hipStream_t stream) {
    const float* x     = (const float*)d_in[0];
    const float* probs = (const float*)d_in[1];
    const float* W1    = (const float*)d_in[2];
    const float* b1    = (const float*)d_in[3];
    const float* W2    = (const float*)d_in[4];
    const float* b2    = (const float*)d_in[5];
    const float* W3    = (const float*)d_in[6];
    const float* b3    = (const float*)d_in[7];

    hipLaunchKernelGGL(build_image, dim3(1), dim3(1024), 0, stream,
                       W1, b1, W2, b2, W3, b3, (char*)d_ws);
    const int nrows = in_sizes[0] / 32;          // 524288
    hipLaunchKernelGGL(moe_fused, dim3(nrows / 512), dim3(512), 0, stream,
                       x, probs, (const char*)d_ws, (float*)d_out);
}